// Round 12
// baseline (231.762 us; speedup 1.0000x reference)
//
#include <hip/hip_runtime.h>
#include <hip/hip_bf16.h>

// CrossAttention: b=4, n=1024, qs=256, heads=8, dim_head=64, bottleneck=40.
// Attention = full 8192x8192 softmax-attention per batch over D=64.
//
// R12: blind-spot round (attn monopolizes top-5; accounting shows qkv~65 +
// out~43 + overhead~20 around attn 74).
//  - out: grid 1024 (4 rows x 256 cols, 4 blocks/CU = 16 waves/CU) + R10's
//    ping-pong loop. Was 1 block/CU -> latency-naked.
//  - qkv: stage-1 k-split x2 (serial chain 64->32 iters, all 512 threads
//    active) + unroll hints so loads hoist.
//  - attn: frozen from R8-R11 (73.7us).
//
// Workspace: Q 4MB | K_sw 4MB | V_sw 4MB | Opart 2x8MB | psum 2x128KB ~ 28.3MB.

#define B_    4
#define H_    8
#define NSEQ  1024
#define SEQ   8192        // H_*NSEQ
#define DH    64
#define QS    256
#define INNER 512
#define QSCALE 0.18033688011112042f   // (1/sqrt(64)) * log2(e)

#define KVSW_BATCH 524288             // elems per batch in K_sw / V_sw

typedef __bf16 bf16x8 __attribute__((ext_vector_type(8)));
typedef float floatx4 __attribute__((ext_vector_type(4)));

// ---------------- kernel 1: QKV projections + fragment-order swizzle ----------------
// grid 256 (b*64 + nblk), 512 threads, 16 x-rows per block.
__global__ __launch_bounds__(512) void qkv_kernel(
    const float* __restrict__ x,
    const float* __restrict__ wq1, const float* __restrict__ wq2,
    const float* __restrict__ wk1, const float* __restrict__ wk2,
    const float* __restrict__ wv1, const float* __restrict__ wv2,
    __hip_bfloat16* __restrict__ Qg, __hip_bfloat16* __restrict__ KSg,
    __hip_bfloat16* __restrict__ VSg)
{
  const int tid  = threadIdx.x;
  const int b    = blockIdx.x >> 6;
  const int nblk = blockIdx.x & 63;
  const int n0   = nblk << 4;

  __shared__ __align__(16) float xs[16][260];
  __shared__ __align__(16) float tb2[2][3][16][40];   // k-split partials
  __shared__ __align__(16) float tb[3][16][40];
  __shared__ __align__(16) __hip_bfloat16 qb[16][520];
  __shared__ __align__(16) __hip_bfloat16 kb[16][520];
  __shared__ __align__(16) __hip_bfloat16 vb[512][20];   // [h*64+d][n_local]

  for (int i = tid; i < 16 * 256; i += 512) {
    const int r = i >> 8, c = i & 255;
    xs[r][c] = x[((size_t)b * NSEQ + n0 + r) * QS + c];
  }
  __syncthreads();

  // stage 1a: bottleneck partials, k-split x2.
  // 960 tasks = 2 khalf x 3 proj x 16 rows x 10 col-quads.
  for (int t = tid; t < 960; t += 512) {
    const int ks  = (t >= 480) ? 1 : 0;
    const int t2  = t - ks * 480;
    const int p   = t2 / 160;
    const int rem = t2 - p * 160;
    const int r   = rem / 10;
    const int bn  = (rem - r * 10) * 4;
    const float* w1 = (p == 0) ? wq1 : (p == 1) ? wk1 : wv1;
    float a0 = 0.f, a1 = 0.f, a2 = 0.f, a3 = 0.f;
    #pragma unroll 4
    for (int c4 = ks * 32; c4 < ks * 32 + 32; ++c4) {
      const float4 xv = *(const float4*)(&xs[r][c4 * 4]);
      const float4 wa = *(const float4*)(w1 + (c4 * 4 + 0) * 40 + bn);
      const float4 wb = *(const float4*)(w1 + (c4 * 4 + 1) * 40 + bn);
      const float4 wc = *(const float4*)(w1 + (c4 * 4 + 2) * 40 + bn);
      const float4 wd = *(const float4*)(w1 + (c4 * 4 + 3) * 40 + bn);
      a0 += xv.x * wa.x + xv.y * wb.x + xv.z * wc.x + xv.w * wd.x;
      a1 += xv.x * wa.y + xv.y * wb.y + xv.z * wc.y + xv.w * wd.y;
      a2 += xv.x * wa.z + xv.y * wb.z + xv.z * wc.z + xv.w * wd.z;
      a3 += xv.x * wa.w + xv.y * wb.w + xv.z * wc.w + xv.w * wd.w;
    }
    tb2[ks][p][r][bn + 0] = a0; tb2[ks][p][r][bn + 1] = a1;
    tb2[ks][p][r][bn + 2] = a2; tb2[ks][p][r][bn + 3] = a3;
  }
  __syncthreads();

  // stage 1b: combine halves + SiLU on K path.
  if (tid < 480) {
    const int p   = tid / 160;
    const int rem = tid - p * 160;
    const int r   = rem / 10;
    const int bn  = (rem - r * 10) * 4;
    const float4 h0 = *(const float4*)(&tb2[0][p][r][bn]);
    const float4 h1 = *(const float4*)(&tb2[1][p][r][bn]);
    float a0 = h0.x + h1.x, a1 = h0.y + h1.y, a2 = h0.z + h1.z, a3 = h0.w + h1.w;
    if (p == 1) {
      a0 = a0 / (1.f + __expf(-a0));
      a1 = a1 / (1.f + __expf(-a1));
      a2 = a2 / (1.f + __expf(-a2));
      a3 = a3 / (1.f + __expf(-a3));
    }
    tb[p][r][bn + 0] = a0; tb[p][r][bn + 1] = a1;
    tb[p][r][bn + 2] = a2; tb[p][r][bn + 3] = a3;
  }
  __syncthreads();

  // stage 2: 40 -> 512. 3 passes x 512 tasks (pass == projection).
  #pragma unroll
  for (int pass = 0; pass < 3; ++pass) {
    const int p  = pass;
    const int cq = tid & 127;
    const int rq = (tid >> 7) & 3;
    const int c  = cq * 4, r0 = rq * 4;
    const float* w2 = (p == 0) ? wq2 : (p == 1) ? wk2 : wv2;
    const float scale = (p == 0) ? QSCALE : 1.0f;
    float acc[4][4];
    #pragma unroll
    for (int i = 0; i < 4; ++i)
      #pragma unroll
      for (int j = 0; j < 4; ++j) acc[i][j] = 0.f;

    #pragma unroll 2
    for (int jb = 0; jb < 10; ++jb) {
      const float4 w0 = *(const float4*)(w2 + (jb * 4 + 0) * INNER + c);
      const float4 w1r = *(const float4*)(w2 + (jb * 4 + 1) * INNER + c);
      const float4 w2r = *(const float4*)(w2 + (jb * 4 + 2) * INNER + c);
      const float4 w3 = *(const float4*)(w2 + (jb * 4 + 3) * INNER + c);
      #pragma unroll
      for (int ri = 0; ri < 4; ++ri) {
        const float4 tv = *(const float4*)(&tb[p][r0 + ri][jb * 4]);
        acc[ri][0] += tv.x * w0.x + tv.y * w1r.x + tv.z * w2r.x + tv.w * w3.x;
        acc[ri][1] += tv.x * w0.y + tv.y * w1r.y + tv.z * w2r.y + tv.w * w3.y;
        acc[ri][2] += tv.x * w0.z + tv.y * w1r.z + tv.z * w2r.z + tv.w * w3.z;
        acc[ri][3] += tv.x * w0.w + tv.y * w1r.w + tv.z * w2r.w + tv.w * w3.w;
      }
    }
    #pragma unroll
    for (int ri = 0; ri < 4; ++ri)
      #pragma unroll
      for (int ci = 0; ci < 4; ++ci) {
        const int cc = c + ci;
        const float v = acc[ri][ci] * scale;
        if (p == 0)      qb[r0 + ri][cc] = __float2bfloat16(v);
        else if (p == 1) kb[r0 + ri][cc] = __float2bfloat16(v);
        else             vb[cc][r0 + ri] = __float2bfloat16(v);
      }
  }
  __syncthreads();

  // ---- Q write ----
  for (int i = tid; i < 1024; i += 512) {
    const int h  = i >> 7;
    const int r  = (i >> 3) & 15;
    const int d8 = i & 7;
    *(float4*)(Qg + ((size_t)b * SEQ + h * NSEQ + n0 + r) * DH + d8 * 8) =
        *(const float4*)(&qb[r][h * 64 + d8 * 8]);
  }

  // ---- K_sw write (t16 = h*64+nblk) ----
  for (int i = tid; i < 1024; i += 512) {
    const int h    = i >> 7;
    const int ks   = (i >> 6) & 1;
    const int quad = (i >> 4) & 3;
    const int r    = i & 15;
    const int lane = quad * 16 + r;
    const size_t dst = (size_t)b * KVSW_BATCH
        + ((size_t)((h * 64 + nblk) * 2 + ks) * 64 + lane) * 8;
    *(float4*)(KSg + dst) = *(const float4*)(&kb[r][h * 64 + ks * 32 + quad * 8]);
  }

  // ---- V_sw write ----
  {
    const int st  = nblk & 1;
    const int p32 = nblk >> 1;
    for (int i = tid; i < 2048; i += 512) {
      const int h   = i >> 8;
      const int dnt = (i >> 6) & 3;
      const int dm  = (i >> 2) & 15;
      const int rg  = i & 3;
      const int lane = rg * 16 + dm;
      const size_t dst = (size_t)b * KVSW_BATCH
          + ((size_t)((h * 32 + p32) * 4 + dnt) * 64 + lane) * 8 + st * 4;
      *(uint2*)(VSg + dst) = *(const uint2*)(&vb[h * 64 + dnt * 16 + dm][rg * 4]);
    }
  }
}

// ---------------- kernel 2: attention, kv-split partial blocks (frozen R8-R11) ----------------
struct PairBuf {
  bf16x8 k[2][2];   // [strip][k-span]
  bf16x8 v[4];      // [d-tile]
};

__global__ __launch_bounds__(256, 3) void attn_kernel(
    const __hip_bfloat16* __restrict__ Qg,
    const __hip_bfloat16* __restrict__ KSg,
    const __hip_bfloat16* __restrict__ VSg,
    float* __restrict__ OPg,       // [2][B_][SEQ][DH]
    float* __restrict__ PSg)       // [2][B_][SEQ]
{
  __shared__ float Osh[4][16][68];
  __shared__ float psums[4][64];

  const int tid  = threadIdx.x;
  const int wave = tid >> 6;
  const int lane = tid & 63;
  const int lrow = lane & 15;
  const int quad = lane >> 4;

  const int xcd   = blockIdx.x & 7;
  const int idx   = blockIdx.x >> 3;       // [0,128)
  const int b     = xcd >> 1;
  const int half  = idx & 1;
  const int qtile = (xcd & 1) * 64 + (idx >> 1);
  const int qbase = qtile * 64;

  const __hip_bfloat16* Qb  = Qg + ((size_t)b * SEQ + qbase) * DH;
  const __hip_bfloat16* kp0 = KSg + (size_t)b * KVSW_BATCH + half * 262144
                              + (size_t)wave * 65536 + lane * 8;
  const __hip_bfloat16* vp0 = VSg + (size_t)b * KVSW_BATCH + half * 262144
                              + (size_t)wave * 65536 + lane * 8;

  bf16x8 qf[4][2];
  #pragma unroll
  for (int mt = 0; mt < 4; ++mt)
    #pragma unroll
    for (int s = 0; s < 2; ++s)
      qf[mt][s] = *(const bf16x8*)(Qb + (mt * 16 + lrow) * DH + s * 32 + quad * 8);

  floatx4 oacc[4][4];   // [mt][dnt] — 64 acc regs (unified budget)
  #pragma unroll
  for (int mt = 0; mt < 4; ++mt)
    #pragma unroll
    for (int dnt = 0; dnt < 4; ++dnt)
      oacc[mt][dnt] = (floatx4){0.f, 0.f, 0.f, 0.f};
  float psum[4] = {0.f, 0.f, 0.f, 0.f};

  #pragma unroll 2
  for (int pair = 0; pair < 32; ++pair) {
    PairBuf pb;
    const __hip_bfloat16* kp = kp0 + pair * 2048;
    pb.k[0][0] = *(const bf16x8*)(kp);
    pb.k[0][1] = *(const bf16x8*)(kp + 512);
    pb.k[1][0] = *(const bf16x8*)(kp + 1024);
    pb.k[1][1] = *(const bf16x8*)(kp + 1536);
    const __hip_bfloat16* vp = vp0 + pair * 2048;
    #pragma unroll
    for (int dnt = 0; dnt < 4; ++dnt)
      pb.v[dnt] = *(const bf16x8*)(vp + dnt * 512);

    #pragma unroll
    for (int mt = 0; mt < 4; ++mt) {
      floatx4 s0 = (floatx4){0.f, 0.f, 0.f, 0.f};
      floatx4 s1 = (floatx4){0.f, 0.f, 0.f, 0.f};
      s0 = __builtin_amdgcn_mfma_f32_16x16x32_bf16(pb.k[0][0], qf[mt][0], s0, 0, 0, 0);
      s0 = __builtin_amdgcn_mfma_f32_16x16x32_bf16(pb.k[0][1], qf[mt][1], s0, 0, 0, 0);
      s1 = __builtin_amdgcn_mfma_f32_16x16x32_bf16(pb.k[1][0], qf[mt][0], s1, 0, 0, 0);
      s1 = __builtin_amdgcn_mfma_f32_16x16x32_bf16(pb.k[1][1], qf[mt][1], s1, 0, 0, 0);
      float p[8];
      #pragma unroll
      for (int r = 0; r < 4; ++r) {
        p[r]     = __builtin_amdgcn_exp2f(s0[r]);
        p[4 + r] = __builtin_amdgcn_exp2f(s1[r]);
      }
      psum[mt] += ((p[0] + p[1]) + (p[2] + p[3])) + ((p[4] + p[5]) + (p[6] + p[7]));
      bf16x8 pa;
      #pragma unroll
      for (int j = 0; j < 8; ++j) pa[j] = (__bf16)p[j];
      #pragma unroll
      for (int dnt = 0; dnt < 4; ++dnt)
        oacc[mt][dnt] = __builtin_amdgcn_mfma_f32_16x16x32_bf16(pa, pb.v[dnt], oacc[mt][dnt], 0, 0, 0);
    }
  }

  #pragma unroll
  for (int mt = 0; mt < 4; ++mt) {
    float s = psum[mt];
    s += __shfl_xor(s, 16, 64);
    s += __shfl_xor(s, 32, 64);
    psum[mt] = s;
  }
  if (quad == 0) {
    #pragma unroll
    for (int mt = 0; mt < 4; ++mt)
      psums[wave][mt * 16 + lrow] = psum[mt];
  }

  const size_t opbase = ((size_t)half * B_ + b) * SEQ + qbase;

  #pragma unroll
  for (int mt = 0; mt < 4; ++mt) {
    #pragma unroll
    for (int dnt = 0; dnt < 4; ++dnt)
      #pragma unroll
      for (int r = 0; r < 4; ++r)
        Osh[wave][quad * 4 + r][dnt * 16 + lrow] = oacc[mt][dnt][r];
    __syncthreads();

    {
      const int q16 = tid >> 4;
      const int d0  = (tid & 15) * 4;
      float4 a0 = *(const float4*)(&Osh[0][q16][d0]);
      float4 a1 = *(const float4*)(&Osh[1][q16][d0]);
      float4 a2 = *(const float4*)(&Osh[2][q16][d0]);
      float4 a3 = *(const float4*)(&Osh[3][q16][d0]);
      float4 res;
      res.x = (a0.x + a1.x) + (a2.x + a3.x);
      res.y = (a0.y + a1.y) + (a2.y + a3.y);
      res.z = (a0.z + a1.z) + (a2.z + a3.z);
      res.w = (a0.w + a1.w) + (a2.w + a3.w);
      *(float4*)(OPg + (opbase + mt * 16 + q16) * DH + d0) = res;
    }
    if (mt == 0 && tid < 64) {
      const float tot = (psums[0][tid] + psums[1][tid]) + (psums[2][tid] + psums[3][tid]);
      PSg[opbase + tid] = tot;
    }
    __syncthreads();
  }
}

// ---------------- kernel 3: out = merge(Opart)/denom @ wo + bo ----------------
// grid 1024 (b*256 + nb4): 4 rows x 256 cols per block, 256 threads,
// thread = 1 row x 4 cols, 4 blocks/CU (16 waves/CU). wo L1-shared in phase.
__global__ __launch_bounds__(256, 4) void out_kernel(
    const float* __restrict__ OPg, const float* __restrict__ PSg,
    const float* __restrict__ wo, const float* __restrict__ bo,
    float* __restrict__ out)
{
  const int tid = threadIdx.x;
  const int b   = blockIdx.x >> 8;
  const int nb4 = blockIdx.x & 255;
  const int n0  = nb4 * 4;

  __shared__ __align__(16) float os[4][516];
  __shared__ float invs[4][8];

  if (tid < 32) {
    const int r = tid >> 3, h = tid & 7;
    const size_t row = (size_t)b * SEQ + h * NSEQ + n0 + r;
    invs[r][h] = 1.0f / (PSg[row] + PSg[(size_t)B_ * SEQ + row]);
  }
  __syncthreads();

  // gather + merge halves + normalize (512 float4 tasks)
  for (int i = tid; i < 512; i += 256) {
    const int r  = i >> 7;
    const int c4 = (i & 127) * 4;
    const int h  = c4 >> 6;
    const size_t idx = ((size_t)b * SEQ + h * NSEQ + n0 + r) * DH + (c4 & 63);
    const float4 p0 = *(const float4*)(OPg + idx);
    const float4 p1 = *(const float4*)(OPg + (size_t)B_ * SEQ * DH + idx);
    const float inv = invs[r][h];
    float4 m;
    m.x = (p0.x + p1.x) * inv;
    m.y = (p0.y + p1.y) * inv;
    m.z = (p0.z + p1.z) * inv;
    m.w = (p0.w + p1.w) * inv;
    *(float4*)(&os[r][c4]) = m;
  }
  __syncthreads();

  const int oq = tid & 63;      // col group: o = oq*4 (wave-contiguous)
  const int r  = tid >> 6;      // row (wave-uniform -> os reads broadcast)
  const int o  = oq * 4;

  float a0 = 0.f, a1 = 0.f, a2 = 0.f, a3 = 0.f;

  // ping-pong prefetch of wo rows
  float4 wa0 = *(const float4*)(wo + 0 * QS + o);
  float4 wa1 = *(const float4*)(wo + 1 * QS + o);
  float4 wa2 = *(const float4*)(wo + 2 * QS + o);
  float4 wa3 = *(const float4*)(wo + 3 * QS + o);

  for (int jb = 0; jb < 128; ++jb) {
    const int jn = (jb < 127) ? jb + 1 : 127;
    float4 wb0 = *(const float4*)(wo + (jn * 4 + 0) * QS + o);
    float4 wb1 = *(const float4*)(wo + (jn * 4 + 1) * QS + o);
    float4 wb2 = *(const float4*)(wo + (jn * 4 + 2) * QS + o);
    float4 wb3 = *(const float4*)(wo + (jn * 4 + 3) * QS + o);

    const float4 ov = *(const float4*)(&os[r][jb * 4]);   // wave-broadcast
    a0 += ov.x * wa0.x + ov.y * wa1.x + ov.z * wa2.x + ov.w * wa3.x;
    a1 += ov.x * wa0.y + ov.y * wa1.y + ov.z * wa2.y + ov.w * wa3.y;
    a2 += ov.x * wa0.z + ov.y * wa1.z + ov.z * wa2.z + ov.w * wa3.z;
    a3 += ov.x * wa0.w + ov.y * wa1.w + ov.z * wa2.w + ov.w * wa3.w;

    wa0 = wb0; wa1 = wb1; wa2 = wb2; wa3 = wb3;
  }

  const float4 bv = *(const float4*)(bo + o);
  float4 res;
  res.x = a0 + bv.x; res.y = a1 + bv.y; res.z = a2 + bv.z; res.w = a3 + bv.w;
  *(float4*)(out + ((size_t)b * NSEQ + n0 + r) * QS + o) = res;
}

extern "C" void kernel_launch(void* const* d_in, const int* in_sizes, int n_in,
                              void* d_out, int out_size, void* d_ws, size_t ws_size,
                              hipStream_t stream) {
  const float* x   = (const float*)d_in[0];
  const float* wq1 = (const float*)d_in[1];
  const float* wq2 = (const float*)d_in[2];
  const float* wk1 = (const float*)d_in[3];
  const float* wk2 = (const float*)d_in[4];
  const float* wv1 = (const float*)d_in[5];
  const float* wv2 = (const float*)d_in[6];
  const float* wo  = (const float*)d_in[7];
  const float* bo  = (const float*)d_in[8];
  float* out = (float*)d_out;

  __hip_bfloat16* Qg  = (__hip_bfloat16*)d_ws;
  __hip_bfloat16* KSg = Qg + (size_t)B_ * SEQ * DH;
  __hip_bfloat16* VSg = KSg + (size_t)B_ * KVSW_BATCH;
  float*          OPg = (float*)(VSg + (size_t)B_ * KVSW_BATCH);   // [2][B_][SEQ][DH]
  float*          PSg = OPg + 2 * (size_t)B_ * SEQ * DH;           // [2][B_][SEQ]

  qkv_kernel<<<256, 512, 0, stream>>>(x, wq1, wq2, wk1, wk2, wv1, wv2, Qg, KSg, VSg);
  attn_kernel<<<1024, 256, 0, stream>>>(Qg, KSg, VSg, OPg, PSg);
  out_kernel<<<1024, 256, 0, stream>>>(OPg, PSg, wo, bo, out);
}

// Round 13
// 196.561 us; speedup vs baseline: 1.1791x; 1.1791x over previous
//
#include <hip/hip_runtime.h>
#include <hip/hip_bf16.h>

// CrossAttention: b=4, n=1024, qs=256, heads=8, dim_head=64, bottleneck=40.
// Attention = full 8192x8192 softmax-attention per batch over D=64.
//
// R13:
//  - out: wo staged through LDS (R12 showed per-wave L2 streaming of wo =
//    8MB/CU = the 75us). grid 256, 512 thr, K-tiles of 16 rows, reg->LDS
//    double buffer, one barrier/tile. wo crosses L2 once per block.
//  - qkv: R12 structure at 1024 threads (4 waves/SIMD) — attacks the
//    latency exposure that pinned every 2-wave/SIMD variant at ~60us.
//  - attn: frozen (73.7us, MfmaUtil 40.9%).
//
// Workspace: Q 4MB | K_sw 4MB | V_sw 4MB | Opart 2x8MB | psum 2x128KB ~ 28.3MB.

#define B_    4
#define H_    8
#define NSEQ  1024
#define SEQ   8192        // H_*NSEQ
#define DH    64
#define QS    256
#define INNER 512
#define QSCALE 0.18033688011112042f   // (1/sqrt(64)) * log2(e)

#define KVSW_BATCH 524288             // elems per batch in K_sw / V_sw

typedef __bf16 bf16x8 __attribute__((ext_vector_type(8)));
typedef float floatx4 __attribute__((ext_vector_type(4)));

// ---------------- kernel 1: QKV projections + fragment-order swizzle ----------------
// grid 256 (b*64 + nblk), 1024 threads, 16 x-rows per block.
__global__ __launch_bounds__(1024) void qkv_kernel(
    const float* __restrict__ x,
    const float* __restrict__ wq1, const float* __restrict__ wq2,
    const float* __restrict__ wk1, const float* __restrict__ wk2,
    const float* __restrict__ wv1, const float* __restrict__ wv2,
    __hip_bfloat16* __restrict__ Qg, __hip_bfloat16* __restrict__ KSg,
    __hip_bfloat16* __restrict__ VSg)
{
  const int tid  = threadIdx.x;
  const int b    = blockIdx.x >> 6;
  const int nblk = blockIdx.x & 63;
  const int n0   = nblk << 4;

  __shared__ __align__(16) float xs[16][260];
  __shared__ __align__(16) float tb2[2][3][16][40];   // k-split partials
  __shared__ __align__(16) float tb[3][16][40];
  __shared__ __align__(16) __hip_bfloat16 qb[16][520];
  __shared__ __align__(16) __hip_bfloat16 kb[16][520];
  __shared__ __align__(16) __hip_bfloat16 vb[512][20];   // [h*64+d][n_local]

  for (int i = tid; i < 16 * 256; i += 1024) {
    const int r = i >> 8, c = i & 255;
    xs[r][c] = x[((size_t)b * NSEQ + n0 + r) * QS + c];
  }
  __syncthreads();

  // stage 1a: bottleneck partials, k-split x2. 960 tasks, one round.
  if (tid < 960) {
    const int ks  = (tid >= 480) ? 1 : 0;
    const int t2  = tid - ks * 480;
    const int p   = t2 / 160;
    const int rem = t2 - p * 160;
    const int r   = rem / 10;
    const int bn  = (rem - r * 10) * 4;
    const float* w1 = (p == 0) ? wq1 : (p == 1) ? wk1 : wv1;
    float a0 = 0.f, a1 = 0.f, a2 = 0.f, a3 = 0.f;
    #pragma unroll 4
    for (int c4 = ks * 32; c4 < ks * 32 + 32; ++c4) {
      const float4 xv = *(const float4*)(&xs[r][c4 * 4]);
      const float4 wa = *(const float4*)(w1 + (c4 * 4 + 0) * 40 + bn);
      const float4 wb = *(const float4*)(w1 + (c4 * 4 + 1) * 40 + bn);
      const float4 wc = *(const float4*)(w1 + (c4 * 4 + 2) * 40 + bn);
      const float4 wd = *(const float4*)(w1 + (c4 * 4 + 3) * 40 + bn);
      a0 += xv.x * wa.x + xv.y * wb.x + xv.z * wc.x + xv.w * wd.x;
      a1 += xv.x * wa.y + xv.y * wb.y + xv.z * wc.y + xv.w * wd.y;
      a2 += xv.x * wa.z + xv.y * wb.z + xv.z * wc.z + xv.w * wd.z;
      a3 += xv.x * wa.w + xv.y * wb.w + xv.z * wc.w + xv.w * wd.w;
    }
    tb2[ks][p][r][bn + 0] = a0; tb2[ks][p][r][bn + 1] = a1;
    tb2[ks][p][r][bn + 2] = a2; tb2[ks][p][r][bn + 3] = a3;
  }
  __syncthreads();

  // stage 1b: combine halves + SiLU on K path.
  if (tid < 480) {
    const int p   = tid / 160;
    const int rem = tid - p * 160;
    const int r   = rem / 10;
    const int bn  = (rem - r * 10) * 4;
    const float4 h0 = *(const float4*)(&tb2[0][p][r][bn]);
    const float4 h1 = *(const float4*)(&tb2[1][p][r][bn]);
    float a0 = h0.x + h1.x, a1 = h0.y + h1.y, a2 = h0.z + h1.z, a3 = h0.w + h1.w;
    if (p == 1) {
      a0 = a0 / (1.f + __expf(-a0));
      a1 = a1 / (1.f + __expf(-a1));
      a2 = a2 / (1.f + __expf(-a2));
      a3 = a3 / (1.f + __expf(-a3));
    }
    tb[p][r][bn + 0] = a0; tb[p][r][bn + 1] = a1;
    tb[p][r][bn + 2] = a2; tb[p][r][bn + 3] = a3;
  }
  __syncthreads();

  // stage 2: 40 -> 512. 3 passes (pass == projection), thread = 2 rows x 4 cols.
  #pragma unroll
  for (int pass = 0; pass < 3; ++pass) {
    const int p  = pass;
    const int cq = tid & 127;
    const int rq = (tid >> 7) & 7;
    const int c  = cq * 4, r0 = rq * 2;
    const float* w2 = (p == 0) ? wq2 : (p == 1) ? wk2 : wv2;
    const float scale = (p == 0) ? QSCALE : 1.0f;
    float acc[2][4];
    #pragma unroll
    for (int i = 0; i < 2; ++i)
      #pragma unroll
      for (int j = 0; j < 4; ++j) acc[i][j] = 0.f;

    #pragma unroll 2
    for (int jb = 0; jb < 10; ++jb) {
      const float4 w0 = *(const float4*)(w2 + (jb * 4 + 0) * INNER + c);
      const float4 w1r = *(const float4*)(w2 + (jb * 4 + 1) * INNER + c);
      const float4 w2r = *(const float4*)(w2 + (jb * 4 + 2) * INNER + c);
      const float4 w3 = *(const float4*)(w2 + (jb * 4 + 3) * INNER + c);
      #pragma unroll
      for (int ri = 0; ri < 2; ++ri) {
        const float4 tv = *(const float4*)(&tb[p][r0 + ri][jb * 4]);
        acc[ri][0] += tv.x * w0.x + tv.y * w1r.x + tv.z * w2r.x + tv.w * w3.x;
        acc[ri][1] += tv.x * w0.y + tv.y * w1r.y + tv.z * w2r.y + tv.w * w3.y;
        acc[ri][2] += tv.x * w0.z + tv.y * w1r.z + tv.z * w2r.z + tv.w * w3.z;
        acc[ri][3] += tv.x * w0.w + tv.y * w1r.w + tv.z * w2r.w + tv.w * w3.w;
      }
    }
    #pragma unroll
    for (int ri = 0; ri < 2; ++ri)
      #pragma unroll
      for (int ci = 0; ci < 4; ++ci) {
        const int cc = c + ci;
        const float v = acc[ri][ci] * scale;
        if (p == 0)      qb[r0 + ri][cc] = __float2bfloat16(v);
        else if (p == 1) kb[r0 + ri][cc] = __float2bfloat16(v);
        else             vb[cc][r0 + ri] = __float2bfloat16(v);
      }
  }
  __syncthreads();

  // ---- Q write: 1024 float4 tasks ----
  {
    const int i  = tid;
    const int h  = i >> 7;
    const int r  = (i >> 3) & 15;
    const int d8 = i & 7;
    *(float4*)(Qg + ((size_t)b * SEQ + h * NSEQ + n0 + r) * DH + d8 * 8) =
        *(const float4*)(&qb[r][h * 64 + d8 * 8]);
  }

  // ---- K_sw write: 1024 float4 tasks (t16 = h*64+nblk) ----
  {
    const int i    = tid;
    const int h    = i >> 7;
    const int ks   = (i >> 6) & 1;
    const int quad = (i >> 4) & 3;
    const int r    = i & 15;
    const int lane = quad * 16 + r;
    const size_t dst = (size_t)b * KVSW_BATCH
        + ((size_t)((h * 64 + nblk) * 2 + ks) * 64 + lane) * 8;
    *(float4*)(KSg + dst) = *(const float4*)(&kb[r][h * 64 + ks * 32 + quad * 8]);
  }

  // ---- V_sw write: 2048 uint2 tasks ----
  {
    const int st  = nblk & 1;
    const int p32 = nblk >> 1;
    #pragma unroll
    for (int pass = 0; pass < 2; ++pass) {
      const int i   = tid + pass * 1024;
      const int h   = i >> 8;
      const int dnt = (i >> 6) & 3;
      const int dm  = (i >> 2) & 15;
      const int rg  = i & 3;
      const int lane = rg * 16 + dm;
      const size_t dst = (size_t)b * KVSW_BATCH
          + ((size_t)((h * 32 + p32) * 4 + dnt) * 64 + lane) * 8 + st * 4;
      *(uint2*)(VSg + dst) = *(const uint2*)(&vb[h * 64 + dnt * 16 + dm][rg * 4]);
    }
  }
}

// ---------------- kernel 2: attention, kv-split partial blocks (frozen R8-R12) ----------------
struct PairBuf {
  bf16x8 k[2][2];   // [strip][k-span]
  bf16x8 v[4];      // [d-tile]
};

__global__ __launch_bounds__(256, 3) void attn_kernel(
    const __hip_bfloat16* __restrict__ Qg,
    const __hip_bfloat16* __restrict__ KSg,
    const __hip_bfloat16* __restrict__ VSg,
    float* __restrict__ OPg,       // [2][B_][SEQ][DH]
    float* __restrict__ PSg)       // [2][B_][SEQ]
{
  __shared__ float Osh[4][16][68];
  __shared__ float psums[4][64];

  const int tid  = threadIdx.x;
  const int wave = tid >> 6;
  const int lane = tid & 63;
  const int lrow = lane & 15;
  const int quad = lane >> 4;

  const int xcd   = blockIdx.x & 7;
  const int idx   = blockIdx.x >> 3;       // [0,128)
  const int b     = xcd >> 1;
  const int half  = idx & 1;
  const int qtile = (xcd & 1) * 64 + (idx >> 1);
  const int qbase = qtile * 64;

  const __hip_bfloat16* Qb  = Qg + ((size_t)b * SEQ + qbase) * DH;
  const __hip_bfloat16* kp0 = KSg + (size_t)b * KVSW_BATCH + half * 262144
                              + (size_t)wave * 65536 + lane * 8;
  const __hip_bfloat16* vp0 = VSg + (size_t)b * KVSW_BATCH + half * 262144
                              + (size_t)wave * 65536 + lane * 8;

  bf16x8 qf[4][2];
  #pragma unroll
  for (int mt = 0; mt < 4; ++mt)
    #pragma unroll
    for (int s = 0; s < 2; ++s)
      qf[mt][s] = *(const bf16x8*)(Qb + (mt * 16 + lrow) * DH + s * 32 + quad * 8);

  floatx4 oacc[4][4];   // [mt][dnt] — 64 acc regs (unified budget)
  #pragma unroll
  for (int mt = 0; mt < 4; ++mt)
    #pragma unroll
    for (int dnt = 0; dnt < 4; ++dnt)
      oacc[mt][dnt] = (floatx4){0.f, 0.f, 0.f, 0.f};
  float psum[4] = {0.f, 0.f, 0.f, 0.f};

  #pragma unroll 2
  for (int pair = 0; pair < 32; ++pair) {
    PairBuf pb;
    const __hip_bfloat16* kp = kp0 + pair * 2048;
    pb.k[0][0] = *(const bf16x8*)(kp);
    pb.k[0][1] = *(const bf16x8*)(kp + 512);
    pb.k[1][0] = *(const bf16x8*)(kp + 1024);
    pb.k[1][1] = *(const bf16x8*)(kp + 1536);
    const __hip_bfloat16* vp = vp0 + pair * 2048;
    #pragma unroll
    for (int dnt = 0; dnt < 4; ++dnt)
      pb.v[dnt] = *(const bf16x8*)(vp + dnt * 512);

    #pragma unroll
    for (int mt = 0; mt < 4; ++mt) {
      floatx4 s0 = (floatx4){0.f, 0.f, 0.f, 0.f};
      floatx4 s1 = (floatx4){0.f, 0.f, 0.f, 0.f};
      s0 = __builtin_amdgcn_mfma_f32_16x16x32_bf16(pb.k[0][0], qf[mt][0], s0, 0, 0, 0);
      s0 = __builtin_amdgcn_mfma_f32_16x16x32_bf16(pb.k[0][1], qf[mt][1], s0, 0, 0, 0);
      s1 = __builtin_amdgcn_mfma_f32_16x16x32_bf16(pb.k[1][0], qf[mt][0], s1, 0, 0, 0);
      s1 = __builtin_amdgcn_mfma_f32_16x16x32_bf16(pb.k[1][1], qf[mt][1], s1, 0, 0, 0);
      float p[8];
      #pragma unroll
      for (int r = 0; r < 4; ++r) {
        p[r]     = __builtin_amdgcn_exp2f(s0[r]);
        p[4 + r] = __builtin_amdgcn_exp2f(s1[r]);
      }
      psum[mt] += ((p[0] + p[1]) + (p[2] + p[3])) + ((p[4] + p[5]) + (p[6] + p[7]));
      bf16x8 pa;
      #pragma unroll
      for (int j = 0; j < 8; ++j) pa[j] = (__bf16)p[j];
      #pragma unroll
      for (int dnt = 0; dnt < 4; ++dnt)
        oacc[mt][dnt] = __builtin_amdgcn_mfma_f32_16x16x32_bf16(pa, pb.v[dnt], oacc[mt][dnt], 0, 0, 0);
    }
  }

  #pragma unroll
  for (int mt = 0; mt < 4; ++mt) {
    float s = psum[mt];
    s += __shfl_xor(s, 16, 64);
    s += __shfl_xor(s, 32, 64);
    psum[mt] = s;
  }
  if (quad == 0) {
    #pragma unroll
    for (int mt = 0; mt < 4; ++mt)
      psums[wave][mt * 16 + lrow] = psum[mt];
  }

  const size_t opbase = ((size_t)half * B_ + b) * SEQ + qbase;

  #pragma unroll
  for (int mt = 0; mt < 4; ++mt) {
    #pragma unroll
    for (int dnt = 0; dnt < 4; ++dnt)
      #pragma unroll
      for (int r = 0; r < 4; ++r)
        Osh[wave][quad * 4 + r][dnt * 16 + lrow] = oacc[mt][dnt][r];
    __syncthreads();

    {
      const int q16 = tid >> 4;
      const int d0  = (tid & 15) * 4;
      float4 a0 = *(const float4*)(&Osh[0][q16][d0]);
      float4 a1 = *(const float4*)(&Osh[1][q16][d0]);
      float4 a2 = *(const float4*)(&Osh[2][q16][d0]);
      float4 a3 = *(const float4*)(&Osh[3][q16][d0]);
      float4 res;
      res.x = (a0.x + a1.x) + (a2.x + a3.x);
      res.y = (a0.y + a1.y) + (a2.y + a3.y);
      res.z = (a0.z + a1.z) + (a2.z + a3.z);
      res.w = (a0.w + a1.w) + (a2.w + a3.w);
      *(float4*)(OPg + (opbase + mt * 16 + q16) * DH + d0) = res;
    }
    if (mt == 0 && tid < 64) {
      const float tot = (psums[0][tid] + psums[1][tid]) + (psums[2][tid] + psums[3][tid]);
      PSg[opbase + tid] = tot;
    }
    __syncthreads();
  }
}

// ---------------- kernel 3: out = merge(Opart)/denom @ wo + bo ----------------
// grid 256 (1 block/CU), 512 threads. 16 rows x 256 cols. wo staged through
// LDS in K-tiles of 16 (reg-prefetch double buffer, one barrier per tile).
// Thread = 2 rows x 4 cols; os reads wave-broadcast.
__global__ __launch_bounds__(512) void out_kernel(
    const float* __restrict__ OPg, const float* __restrict__ PSg,
    const float* __restrict__ wo, const float* __restrict__ bo,
    float* __restrict__ out)
{
  const int tid = threadIdx.x;
  const int b   = blockIdx.x >> 6;
  const int n0  = (blockIdx.x & 63) << 4;

  __shared__ __align__(16) float os[16][520];
  __shared__ __align__(16) float wot[2][16][260];
  __shared__ float invs[16][8];

  if (tid < 128) {
    const int r = tid >> 3, h = tid & 7;
    const size_t row = (size_t)b * SEQ + h * NSEQ + n0 + r;
    invs[r][h] = 1.0f / (PSg[row] + PSg[(size_t)B_ * SEQ + row]);
  }
  __syncthreads();

  // gather + merge halves + normalize -> os
  for (int i = tid; i < 2048; i += 512) {
    const int r  = i >> 7;
    const int c4 = (i & 127) * 4;
    const int h  = c4 >> 6;
    const size_t idx = ((size_t)b * SEQ + h * NSEQ + n0 + r) * DH + (c4 & 63);
    const float4 p0 = *(const float4*)(OPg + idx);
    const float4 p1 = *(const float4*)(OPg + (size_t)B_ * SEQ * DH + idx);
    const float inv = invs[r][c4 >> 6];
    float4 m;
    m.x = (p0.x + p1.x) * inv;
    m.y = (p0.y + p1.y) * inv;
    m.z = (p0.z + p1.z) * inv;
    m.w = (p0.w + p1.w) * inv;
    *(float4*)(&os[r][c4]) = m;
  }

  // stage tile 0 of wo (chunks: krow = c>>6, col = (c&63)*4)
  {
    const int c0 = tid, c1 = tid + 512;
    const float4 v0 = *(const float4*)(wo + (size_t)(c0 >> 6) * QS + (c0 & 63) * 4);
    const float4 v1 = *(const float4*)(wo + (size_t)(c1 >> 6) * QS + (c1 & 63) * 4);
    *(float4*)(&wot[0][c0 >> 6][(c0 & 63) * 4]) = v0;
    *(float4*)(&wot[0][c1 >> 6][(c1 & 63) * 4]) = v1;
  }
  __syncthreads();

  const int oq = tid & 63;      // col group: o = oq*4
  const int rq = tid >> 6;      // row pair: rows rq*2, rq*2+1
  const int o  = oq * 4;
  const int r0 = rq * 2;

  float acc[2][4];
  #pragma unroll
  for (int i = 0; i < 2; ++i)
    #pragma unroll
    for (int j = 0; j < 4; ++j) acc[i][j] = 0.f;

  for (int kt = 0; kt < 32; ++kt) {
    const int cur = kt & 1;
    // prefetch next tile into registers (latency hidden by compute below)
    float4 pf0, pf1;
    const int c0 = tid, c1 = tid + 512;
    if (kt < 31) {
      const int kb = (kt + 1) * 16;
      pf0 = *(const float4*)(wo + (size_t)(kb + (c0 >> 6)) * QS + (c0 & 63) * 4);
      pf1 = *(const float4*)(wo + (size_t)(kb + (c1 >> 6)) * QS + (c1 & 63) * 4);
    }

    // compute this tile
    const int kbase = kt * 16;
    #pragma unroll
    for (int kq = 0; kq < 4; ++kq) {
      const float4 ov0 = *(const float4*)(&os[r0][kbase + kq * 4]);       // broadcast
      const float4 ov1 = *(const float4*)(&os[r0 + 1][kbase + kq * 4]);   // broadcast
      #pragma unroll
      for (int j = 0; j < 4; ++j) {
        const float4 w = *(const float4*)(&wot[cur][kq * 4 + j][o]);
        const float a = (j == 0) ? ov0.x : (j == 1) ? ov0.y : (j == 2) ? ov0.z : ov0.w;
        const float bq = (j == 0) ? ov1.x : (j == 1) ? ov1.y : (j == 2) ? ov1.z : ov1.w;
        acc[0][0] += a * w.x; acc[0][1] += a * w.y;
        acc[0][2] += a * w.z; acc[0][3] += a * w.w;
        acc[1][0] += bq * w.x; acc[1][1] += bq * w.y;
        acc[1][2] += bq * w.z; acc[1][3] += bq * w.w;
      }
    }

    if (kt < 31) {
      *(float4*)(&wot[cur ^ 1][c0 >> 6][(c0 & 63) * 4]) = pf0;
      *(float4*)(&wot[cur ^ 1][c1 >> 6][(c1 & 63) * 4]) = pf1;
    }
    __syncthreads();
  }

  const float4 bv = *(const float4*)(bo + o);
  #pragma unroll
  for (int ri = 0; ri < 2; ++ri) {
    float4 res;
    res.x = acc[ri][0] + bv.x;
    res.y = acc[ri][1] + bv.y;
    res.z = acc[ri][2] + bv.z;
    res.w = acc[ri][3] + bv.w;
    *(float4*)(out + ((size_t)b * NSEQ + n0 + r0 + ri) * QS + o) = res;
  }
}

extern "C" void kernel_launch(void* const* d_in, const int* in_sizes, int n_in,
                              void* d_out, int out_size, void* d_ws, size_t ws_size,
                              hipStream_t stream) {
  const float* x   = (const float*)d_in[0];
  const float* wq1 = (const float*)d_in[1];
  const float* wq2 = (const float*)d_in[2];
  const float* wk1 = (const float*)d_in[3];
  const float* wk2 = (const float*)d_in[4];
  const float* wv1 = (const float*)d_in[5];
  const float* wv2 = (const float*)d_in[6];
  const float* wo  = (const float*)d_in[7];
  const float* bo  = (const float*)d_in[8];
  float* out = (float*)d_out;

  __hip_bfloat16* Qg  = (__hip_bfloat16*)d_ws;
  __hip_bfloat16* KSg = Qg + (size_t)B_ * SEQ * DH;
  __hip_bfloat16* VSg = KSg + (size_t)B_ * KVSW_BATCH;
  float*          OPg = (float*)(VSg + (size_t)B_ * KVSW_BATCH);   // [2][B_][SEQ][DH]
  float*          PSg = OPg + 2 * (size_t)B_ * SEQ * DH;           // [2][B_][SEQ]

  qkv_kernel<<<256, 1024, 0, stream>>>(x, wq1, wq2, wk1, wk2, wv1, wv2, Qg, KSg, VSg);
  attn_kernel<<<1024, 256, 0, stream>>>(Qg, KSg, VSg, OPg, PSg);
  out_kernel<<<256, 512, 0, stream>>>(OPg, PSg, wo, bo, out);
}